// Round 15
// baseline (103.177 us; speedup 1.0000x reference)
//
#include <hip/hip_runtime.h>
#include <math.h>

#define LOG_2PI_F 1.8378770664093453f
#define EPS_F 1e-10f
#define NB 32        // batches
#define CV 512       // components per batch (C*V)
#define PPW 8        // points per wave
#define KPL 8        // comps per lane = CV / 64

// Single fused kernel. ws layout (floats):
//   ws[0]        = block-done counter (as unsigned, zeroed per call)
//   ws[1..32]    = boundary-wave accumulators (zeroed per call)
//   ws[64..64+n_waves) = per-wave partial sums (every slot written each call)
// Last finished block aggregates and overwrites out[0..32] (no d_out memset).
__global__ __launch_bounds__(256)
__attribute__((amdgpu_waves_per_eu(2, 4)))
void capsule_fused(
    const float* __restrict__ x,
    const float* __restrict__ vote,
    const float* __restrict__ scales,
    const float* __restrict__ log_pres,
    const int* __restrict__ batch,
    float* __restrict__ out,     // [0]=mean, [1..32]=per-example
    float* __restrict__ ws,
    int n_pts, int n_waves)
{
    __shared__ float part[NB];
    __shared__ unsigned int is_last;

    const int tid  = threadIdx.x;
    const int lane = tid & 63;
    // readfirstlane: make wave index provably uniform -> x loads become s_loads
    const int wloc = __builtin_amdgcn_readfirstlane(tid >> 6);
    const int wave = blockIdx.x * 4 + wloc;
    const int p0   = wave * PPW;

    unsigned int* ctr  = (unsigned int*)ws;
    float*        bnd  = ws + 1;
    float*        wsum = ws + 64;

    if (p0 < n_pts) {
        // batch of point p0 + (lane&7); clamped for tail safety
        int pidx = p0 + (lane & 7);
        if (pidx >= n_pts) pidx = n_pts - 1;
        const int  pb8     = batch[pidx];
        const int  b0      = __builtin_amdgcn_readfirstlane(pb8);
        const bool uniform = (__ballot(pb8 == b0) == ~0ull);

        // packed per-comp params in registers: a* = mu_d * inv, inv, coef
        float a0[KPL], a1[KPL], a2[KPL], a3[KPL], a4[KPL], a5[KPL];
        float ainv[KPL], acoef[KPL];

        auto load_params = [&](int b) {
            #pragma unroll
            for (int j = 0; j < KPL; ++j) {
                const int c = b * CV + lane + 64 * j;   // coalesced
                float s   = fmaxf(scales[c], EPS_F);
                float inv = 1.0f / s;
                const float* mu = vote + (size_t)c * 6;
                a0[j] = mu[0] * inv;
                a1[j] = mu[1] * inv;
                a2[j] = mu[2] * inv;
                a3[j] = mu[3] * inv;
                a4[j] = mu[4] * inv;
                a5[j] = mu[5] * inv;
                ainv[j]  = inv;
                acoef[j] = log_pres[c] - 6.0f * __logf(s) - 3.0f * LOG_2PI_F;
            }
        };

        load_params(b0);

        // per-point LSE; lp valid on all lanes
        auto lse = [&](float x0, float x1, float x2,
                       float x3, float x4, float x5) -> float {
            float l[KPL];
            #pragma unroll
            for (int j = 0; j < KPL; ++j) {
                float z, acc;
                z = fmaf(x0, ainv[j], -a0[j]); acc = z * z;
                z = fmaf(x1, ainv[j], -a1[j]); acc = fmaf(z, z, acc);
                z = fmaf(x2, ainv[j], -a2[j]); acc = fmaf(z, z, acc);
                z = fmaf(x3, ainv[j], -a3[j]); acc = fmaf(z, z, acc);
                z = fmaf(x4, ainv[j], -a4[j]); acc = fmaf(z, z, acc);
                z = fmaf(x5, ainv[j], -a5[j]); acc = fmaf(z, z, acc);
                l[j] = fmaf(acc, -0.5f, acoef[j]);
            }
            float lm = fmaxf(fmaxf(fmaxf(l[0], l[1]), fmaxf(l[2], l[3])),
                             fmaxf(fmaxf(l[4], l[5]), fmaxf(l[6], l[7])));
            #pragma unroll
            for (int off = 1; off <= 32; off <<= 1)
                lm = fmaxf(lm, __shfl_xor(lm, off, 64));
            float e0 = __expf(l[0] - lm) + __expf(l[1] - lm);
            float e1 = __expf(l[2] - lm) + __expf(l[3] - lm);
            float e2 = __expf(l[4] - lm) + __expf(l[5] - lm);
            float e3 = __expf(l[6] - lm) + __expf(l[7] - lm);
            float es = (e0 + e1) + (e2 + e3);
            #pragma unroll
            for (int off = 1; off <= 32; off <<= 1)
                es += __shfl_xor(es, off, 64);
            return lm + __logf(es);
        };

        if (uniform && p0 + PPW <= n_pts) {
            // hot path: 8 full points, one batch; x software-prefetched
            const float* xp = x + (size_t)p0 * 6;
            float cx0 = xp[0], cx1 = xp[1], cx2 = xp[2],
                  cx3 = xp[3], cx4 = xp[4], cx5 = xp[5];
            float wavesum = 0.0f;
            #pragma unroll
            for (int q = 0; q < PPW; ++q) {
                const float x0 = cx0, x1 = cx1, x2 = cx2,
                            x3 = cx3, x4 = cx4, x5 = cx5;
                if (q + 1 < PPW) {
                    const float* xn = x + (size_t)(p0 + q + 1) * 6;
                    cx0 = xn[0]; cx1 = xn[1]; cx2 = xn[2];
                    cx3 = xn[3]; cx4 = xn[4]; cx5 = xn[5];
                }
                wavesum += lse(x0, x1, x2, x3, x4, x5);
            }
            if (lane == 0) wsum[wave] = wavesum;   // unique slot, no RMW
        } else {
            // rare: batch-boundary or ragged-tail wave -> atomics into bnd
            if (lane == 0) wsum[wave] = 0.0f;
            int cur_b = b0;
            for (int q = 0; q < PPW; ++q) {
                const int p = p0 + q;
                if (p >= n_pts) break;
                const int pb = batch[p];
                if (pb != cur_b) { load_params(pb); cur_b = pb; }
                const float* xp = x + (size_t)p * 6;
                float lp = lse(xp[0], xp[1], xp[2], xp[3], xp[4], xp[5]);
                if (lane == 0) atomicAdd(&bnd[cur_b], lp);
            }
        }
    }

    // ---- last-block-done aggregation (canonical threadfence reduction) ----
    __syncthreads();
    if (tid == 0) {
        __threadfence();                       // release wsum/bnd writes
        unsigned int done = atomicAdd(ctr, 1u);
        is_last = (done == gridDim.x - 1u) ? 1u : 0u;
    }
    __syncthreads();

    if (is_last) {
        __threadfence();                       // acquire others' writes
        if (tid < NB) part[tid] = bnd[tid];    // fold boundary contributions
        __syncthreads();
        for (int w = tid; w < n_waves; w += 256) {
            float s = wsum[w];                 // 0 for boundary waves
            int pi = w * PPW;
            if (pi >= n_pts) pi = n_pts - 1;
            atomicAdd(&part[batch[pi]], s);    // LDS atomic, 32 bins
        }
        __syncthreads();
        if (tid < 64) {
            float v = (tid < NB) ? part[tid] : 0.0f;
            if (tid < NB) out[1 + tid] = v;    // full overwrite, no memset
            #pragma unroll
            for (int off = 32; off >= 1; off >>= 1)
                v += __shfl_xor(v, off, 64);
            if (tid == 0) out[0] = v * (1.0f / NB);
        }
    }
}

extern "C" void kernel_launch(void* const* d_in, const int* in_sizes, int n_in,
                              void* d_out, int out_size, void* d_ws, size_t ws_size,
                              hipStream_t stream) {
    const float* x        = (const float*)d_in[0];
    const float* vote     = (const float*)d_in[1];
    const float* scales   = (const float*)d_in[2];
    const float* log_pres = (const float*)d_in[3];
    const int*   batch    = (const int*)d_in[4];
    float* out = (float*)d_out;
    float* ws  = (float*)d_ws;

    int n_pts   = in_sizes[0] / 6;
    int n_waves = (n_pts + PPW - 1) / PPW;

    // zero the counter + boundary bins (d_ws poisoned 0xAA each call);
    // wsum region needs no zeroing (every slot written each call)
    hipMemsetAsync(d_ws, 0, 256, stream);

    int n_blocks = (n_waves + 3) / 4;          // 4 waves (256 thr) per block
    capsule_fused<<<n_blocks, 256, 0, stream>>>(x, vote, scales, log_pres,
                                                batch, out, ws, n_pts, n_waves);
}

// Round 16
// 98.467 us; speedup vs baseline: 1.0478x; 1.0478x over previous
//
#include <hip/hip_runtime.h>
#include <math.h>

#define LOG_2PI_F 1.8378770664093453f
#define EPS_F 1e-10f
#define NB 32        // batches
#define CV 512       // components per batch (C*V)
#define PPW 8        // points per wave
#define KPL 8        // comps per lane = CV / 64

// Round-10 two-kernel structure (best measured) + batched-point hot path:
// all 64 logits (8 points x 8 comps) computed first, then the 6-step
// butterflies carry 8 independent values per step (ILP hides DS latency).
__global__ __launch_bounds__(256)
__attribute__((amdgpu_waves_per_eu(2, 2)))   // budget 256 VGPR; do NOT squeeze
void capsule_main(
    const float* __restrict__ x,
    const float* __restrict__ vote,
    const float* __restrict__ scales,
    const float* __restrict__ log_pres,
    const int* __restrict__ batch,
    float* __restrict__ out_pe,   // [NB], zeroed; boundary waves atomic here
    float* __restrict__ wsum,     // [n_waves], unique slot per wave
    int n_pts)
{
    const int tid  = threadIdx.x;
    const int lane = tid & 63;
    const int wloc = __builtin_amdgcn_readfirstlane(tid >> 6);
    const int wave = blockIdx.x * 4 + wloc;
    const int p0   = wave * PPW;
    if (p0 >= n_pts) return;

    int pidx = p0 + (lane & 7);
    if (pidx >= n_pts) pidx = n_pts - 1;
    const int  pb8     = batch[pidx];
    const int  b0      = __builtin_amdgcn_readfirstlane(pb8);
    const bool uniform = (__ballot(pb8 == b0) == ~0ull);

    // packed per-comp params in registers: a* = mu_d * inv, inv, coef
    float a0[KPL], a1[KPL], a2[KPL], a3[KPL], a4[KPL], a5[KPL];
    float ainv[KPL], acoef[KPL];

    auto load_params = [&](int b) {
        #pragma unroll
        for (int j = 0; j < KPL; ++j) {
            const int c = b * CV + lane + 64 * j;   // coalesced
            float s   = fmaxf(scales[c], EPS_F);
            float inv = 1.0f / s;
            const float* mu = vote + (size_t)c * 6;
            a0[j] = mu[0] * inv;
            a1[j] = mu[1] * inv;
            a2[j] = mu[2] * inv;
            a3[j] = mu[3] * inv;
            a4[j] = mu[4] * inv;
            a5[j] = mu[5] * inv;
            ainv[j]  = inv;
            acoef[j] = log_pres[c] - 6.0f * __logf(s) - 3.0f * LOG_2PI_F;
        }
    };

    load_params(b0);

    if (uniform && p0 + PPW <= n_pts) {
        // ---- hot path: batch all 8 points ----
        // x values: wave-uniform addresses -> scalar loads
        float xx[PPW][6];
        #pragma unroll
        for (int q = 0; q < PPW; ++q) {
            const float* xp = x + (size_t)(p0 + q) * 6;
            #pragma unroll
            for (int d = 0; d < 6; ++d) xx[q][d] = xp[d];
        }

        // all 64 logits (constant indices -> registers)
        float l[PPW][KPL];
        #pragma unroll
        for (int q = 0; q < PPW; ++q) {
            #pragma unroll
            for (int j = 0; j < KPL; ++j) {
                float z, acc;
                z = fmaf(xx[q][0], ainv[j], -a0[j]); acc = z * z;
                z = fmaf(xx[q][1], ainv[j], -a1[j]); acc = fmaf(z, z, acc);
                z = fmaf(xx[q][2], ainv[j], -a2[j]); acc = fmaf(z, z, acc);
                z = fmaf(xx[q][3], ainv[j], -a3[j]); acc = fmaf(z, z, acc);
                z = fmaf(xx[q][4], ainv[j], -a4[j]); acc = fmaf(z, z, acc);
                z = fmaf(xx[q][5], ainv[j], -a5[j]); acc = fmaf(z, z, acc);
                l[q][j] = fmaf(acc, -0.5f, acoef[j]);
            }
        }

        // lane-local maxes (8 independent 7-op trees)
        float lm[PPW];
        #pragma unroll
        for (int q = 0; q < PPW; ++q)
            lm[q] = fmaxf(fmaxf(fmaxf(l[q][0], l[q][1]), fmaxf(l[q][2], l[q][3])),
                          fmaxf(fmaxf(l[q][4], l[q][5]), fmaxf(l[q][6], l[q][7])));

        // batched max butterfly: 8 independent shuffles per step
        #pragma unroll
        for (int off = 1; off <= 32; off <<= 1) {
            float t[PPW];
            #pragma unroll
            for (int q = 0; q < PPW; ++q) t[q] = __shfl_xor(lm[q], off, 64);
            #pragma unroll
            for (int q = 0; q < PPW; ++q) lm[q] = fmaxf(lm[q], t[q]);
        }

        // batched exp sums
        float es[PPW];
        #pragma unroll
        for (int q = 0; q < PPW; ++q) {
            float e0 = __expf(l[q][0] - lm[q]) + __expf(l[q][1] - lm[q]);
            float e1 = __expf(l[q][2] - lm[q]) + __expf(l[q][3] - lm[q]);
            float e2 = __expf(l[q][4] - lm[q]) + __expf(l[q][5] - lm[q]);
            float e3 = __expf(l[q][6] - lm[q]) + __expf(l[q][7] - lm[q]);
            es[q] = (e0 + e1) + (e2 + e3);
        }

        // batched sum butterfly
        #pragma unroll
        for (int off = 1; off <= 32; off <<= 1) {
            float t[PPW];
            #pragma unroll
            for (int q = 0; q < PPW; ++q) t[q] = __shfl_xor(es[q], off, 64);
            #pragma unroll
            for (int q = 0; q < PPW; ++q) es[q] += t[q];
        }

        float wavesum = 0.0f;
        #pragma unroll
        for (int q = 0; q < PPW; ++q)
            wavesum += lm[q] + __logf(es[q]);

        if (lane == 0) wsum[wave] = wavesum;   // unique slot, no RMW
    } else {
        // rare: batch-boundary or ragged-tail wave -> per-point, atomics
        if (lane == 0) wsum[wave] = 0.0f;
        int cur_b = b0;
        for (int q = 0; q < PPW; ++q) {
            const int p = p0 + q;
            if (p >= n_pts) break;
            const int pb = batch[p];
            if (pb != cur_b) { load_params(pb); cur_b = pb; }
            const float* xp = x + (size_t)p * 6;
            const float x0 = xp[0], x1 = xp[1], x2 = xp[2],
                        x3 = xp[3], x4 = xp[4], x5 = xp[5];
            float l[KPL];
            #pragma unroll
            for (int j = 0; j < KPL; ++j) {
                float z, acc;
                z = fmaf(x0, ainv[j], -a0[j]); acc = z * z;
                z = fmaf(x1, ainv[j], -a1[j]); acc = fmaf(z, z, acc);
                z = fmaf(x2, ainv[j], -a2[j]); acc = fmaf(z, z, acc);
                z = fmaf(x3, ainv[j], -a3[j]); acc = fmaf(z, z, acc);
                z = fmaf(x4, ainv[j], -a4[j]); acc = fmaf(z, z, acc);
                z = fmaf(x5, ainv[j], -a5[j]); acc = fmaf(z, z, acc);
                l[j] = fmaf(acc, -0.5f, acoef[j]);
            }
            float lm = fmaxf(fmaxf(fmaxf(l[0], l[1]), fmaxf(l[2], l[3])),
                             fmaxf(fmaxf(l[4], l[5]), fmaxf(l[6], l[7])));
            #pragma unroll
            for (int off = 1; off <= 32; off <<= 1)
                lm = fmaxf(lm, __shfl_xor(lm, off, 64));
            float es = 0.0f;
            #pragma unroll
            for (int j = 0; j < KPL; ++j) es += __expf(l[j] - lm);
            #pragma unroll
            for (int off = 1; off <= 32; off <<= 1)
                es += __shfl_xor(es, off, 64);
            float lp = lm + __logf(es);
            if (lane == 0) atomicAdd(&out_pe[cur_b], lp);
        }
    }
}

// One block: reduce wsum[] per batch, fold boundary atomics, write mean.
__global__ __launch_bounds__(1024) void final_kernel(
    const float* __restrict__ wsum,
    const int* __restrict__ batch,
    float* __restrict__ d_out,   // [0]=mean, [1..32]=per-example
    int n_waves, int n_pts)
{
    __shared__ float part[NB];
    const int t = threadIdx.x;
    if (t < NB) part[t] = 0.0f;
    __syncthreads();

    for (int w = t; w < n_waves; w += 1024) {
        float s = wsum[w];                       // 0 for boundary waves
        int   pi = w * PPW;
        if (pi >= n_pts) pi = n_pts - 1;
        atomicAdd(&part[batch[pi]], s);          // LDS atomic, 32 bins
    }
    __syncthreads();

    if (t < 64) {
        float v = 0.0f;
        if (t < NB) {
            v = d_out[1 + t] + part[t];          // fold boundary atomics
            d_out[1 + t] = v;
        }
        #pragma unroll
        for (int off = 32; off >= 1; off >>= 1) v += __shfl_xor(v, off, 64);
        if (t == 0) d_out[0] = v * (1.0f / NB);
    }
}

extern "C" void kernel_launch(void* const* d_in, const int* in_sizes, int n_in,
                              void* d_out, int out_size, void* d_ws, size_t ws_size,
                              hipStream_t stream) {
    const float* x        = (const float*)d_in[0];
    const float* vote     = (const float*)d_in[1];
    const float* scales   = (const float*)d_in[2];
    const float* log_pres = (const float*)d_in[3];
    const int*   batch    = (const int*)d_in[4];
    float* out = (float*)d_out;
    float* ws  = (float*)d_ws;

    int n_pts   = in_sizes[0] / 6;
    int n_waves = (n_pts + PPW - 1) / PPW;

    // out re-poisoned to 0xAA before every timed call -> zero it (capture-legal)
    hipMemsetAsync(d_out, 0, (size_t)out_size * sizeof(float), stream);

    int n_blocks = (n_waves + 3) / 4;        // 4 waves (256 threads) per block
    capsule_main<<<n_blocks, 256, 0, stream>>>(x, vote, scales, log_pres, batch,
                                               out + 1, ws, n_pts);

    final_kernel<<<1, 1024, 0, stream>>>(ws, batch, out, n_waves, n_pts);
}

// Round 17
// 91.125 us; speedup vs baseline: 1.1323x; 1.0806x over previous
//
#include <hip/hip_runtime.h>
#include <math.h>

#define LOG_2PI_F 1.8378770664093453f
#define EPS_F 1e-10f
#define NB 32        // batches
#define CV 512       // components per batch (C*V)
#define PPW 8        // points per wave
#define KPL 8        // comps per lane = CV / 64

// Round-10 structure (best measured: 93.0us total, capsule ~28-31us).
// Changes: float2 mu loads (40 vs 64 vmem ops/lane in the cold param phase);
// 2-point interleaved LSE (two independent butterfly chains in flight).
// VGPR target ~100-110 -> (2,4) budget 128, 4-5 waves/EU, no squeeze/spill.
__global__ __launch_bounds__(256)
__attribute__((amdgpu_waves_per_eu(2, 4)))
void capsule_main(
    const float* __restrict__ x,
    const float* __restrict__ vote,
    const float* __restrict__ scales,
    const float* __restrict__ log_pres,
    const int* __restrict__ batch,
    float* __restrict__ out_pe,   // [NB], zeroed; boundary waves atomic here
    float* __restrict__ wsum,     // [n_waves], unique slot per wave
    int n_pts)
{
    const int tid  = threadIdx.x;
    const int lane = tid & 63;
    const int wloc = __builtin_amdgcn_readfirstlane(tid >> 6);
    const int wave = blockIdx.x * 4 + wloc;
    const int p0   = wave * PPW;
    if (p0 >= n_pts) return;

    int pidx = p0 + (lane & 7);
    if (pidx >= n_pts) pidx = n_pts - 1;
    const int  pb8     = batch[pidx];
    const int  b0      = __builtin_amdgcn_readfirstlane(pb8);
    const bool uniform = (__ballot(pb8 == b0) == ~0ull);

    // packed per-comp params in registers: a* = mu_d * inv, inv, coef
    float a0[KPL], a1[KPL], a2[KPL], a3[KPL], a4[KPL], a5[KPL];
    float ainv[KPL], acoef[KPL];

    auto load_params = [&](int b) {
        #pragma unroll
        for (int j = 0; j < KPL; ++j) {
            const int c = b * CV + lane + 64 * j;   // coalesced across lanes
            float s   = fmaxf(scales[c], EPS_F);
            float inv = 1.0f / s;
            // vote + c*6 floats = c*24 bytes -> 8B-aligned: float2 loads
            const float2* mu2 = (const float2*)(vote + (size_t)c * 6);
            float2 m01 = mu2[0], m23 = mu2[1], m45 = mu2[2];
            a0[j] = m01.x * inv;
            a1[j] = m01.y * inv;
            a2[j] = m23.x * inv;
            a3[j] = m23.y * inv;
            a4[j] = m45.x * inv;
            a5[j] = m45.y * inv;
            ainv[j]  = inv;
            acoef[j] = log_pres[c] - 6.0f * __logf(s) - 3.0f * LOG_2PI_F;
        }
    };

    load_params(b0);

    // logits for one point into l[]
    auto logits = [&](const float* xp, float* l) {
        const float x0 = xp[0], x1 = xp[1], x2 = xp[2],
                    x3 = xp[3], x4 = xp[4], x5 = xp[5];
        #pragma unroll
        for (int j = 0; j < KPL; ++j) {
            float z, acc;
            z = fmaf(x0, ainv[j], -a0[j]); acc = z * z;
            z = fmaf(x1, ainv[j], -a1[j]); acc = fmaf(z, z, acc);
            z = fmaf(x2, ainv[j], -a2[j]); acc = fmaf(z, z, acc);
            z = fmaf(x3, ainv[j], -a3[j]); acc = fmaf(z, z, acc);
            z = fmaf(x4, ainv[j], -a4[j]); acc = fmaf(z, z, acc);
            z = fmaf(x5, ainv[j], -a5[j]); acc = fmaf(z, z, acc);
            l[j] = fmaf(acc, -0.5f, acoef[j]);
        }
    };

    auto local_max = [](const float* l) {
        return fmaxf(fmaxf(fmaxf(l[0], l[1]), fmaxf(l[2], l[3])),
                     fmaxf(fmaxf(l[4], l[5]), fmaxf(l[6], l[7])));
    };

    if (uniform && p0 + PPW <= n_pts) {
        // hot path: points in pairs -> two independent reduce chains
        float wavesum = 0.0f;
        #pragma unroll
        for (int q = 0; q < PPW; q += 2) {
            float la[KPL], lb[KPL];
            logits(x + (size_t)(p0 + q) * 6,     la);
            logits(x + (size_t)(p0 + q + 1) * 6, lb);

            float ma = local_max(la);
            float mb = local_max(lb);
            #pragma unroll
            for (int off = 1; off <= 32; off <<= 1) {
                float ta = __shfl_xor(ma, off, 64);
                float tb = __shfl_xor(mb, off, 64);
                ma = fmaxf(ma, ta);
                mb = fmaxf(mb, tb);
            }

            float ea = (__expf(la[0] - ma) + __expf(la[1] - ma))
                     + (__expf(la[2] - ma) + __expf(la[3] - ma))
                     + (__expf(la[4] - ma) + __expf(la[5] - ma))
                     + (__expf(la[6] - ma) + __expf(la[7] - ma));
            float eb = (__expf(lb[0] - mb) + __expf(lb[1] - mb))
                     + (__expf(lb[2] - mb) + __expf(lb[3] - mb))
                     + (__expf(lb[4] - mb) + __expf(lb[5] - mb))
                     + (__expf(lb[6] - mb) + __expf(lb[7] - mb));
            #pragma unroll
            for (int off = 1; off <= 32; off <<= 1) {
                float ta = __shfl_xor(ea, off, 64);
                float tb = __shfl_xor(eb, off, 64);
                ea += ta;
                eb += tb;
            }

            wavesum += (ma + __logf(ea)) + (mb + __logf(eb));
        }
        if (lane == 0) wsum[wave] = wavesum;   // unique slot, no RMW
    } else {
        // rare: batch-boundary or ragged-tail wave -> per-point, atomics
        if (lane == 0) wsum[wave] = 0.0f;
        int cur_b = b0;
        for (int q = 0; q < PPW; ++q) {
            const int p = p0 + q;
            if (p >= n_pts) break;
            const int pb = batch[p];
            if (pb != cur_b) { load_params(pb); cur_b = pb; }
            float l[KPL];
            logits(x + (size_t)p * 6, l);
            float lm = local_max(l);
            #pragma unroll
            for (int off = 1; off <= 32; off <<= 1)
                lm = fmaxf(lm, __shfl_xor(lm, off, 64));
            float es = 0.0f;
            #pragma unroll
            for (int j = 0; j < KPL; ++j) es += __expf(l[j] - lm);
            #pragma unroll
            for (int off = 1; off <= 32; off <<= 1)
                es += __shfl_xor(es, off, 64);
            float lp = lm + __logf(es);
            if (lane == 0) atomicAdd(&out_pe[cur_b], lp);
        }
    }
}

// One block: reduce wsum[] per batch, fold boundary atomics, write mean.
__global__ __launch_bounds__(1024) void final_kernel(
    const float* __restrict__ wsum,
    const int* __restrict__ batch,
    float* __restrict__ d_out,   // [0]=mean, [1..32]=per-example
    int n_waves, int n_pts)
{
    __shared__ float part[NB];
    const int t = threadIdx.x;
    if (t < NB) part[t] = 0.0f;
    __syncthreads();

    for (int w = t; w < n_waves; w += 1024) {
        float s = wsum[w];                       // 0 for boundary waves
        int   pi = w * PPW;
        if (pi >= n_pts) pi = n_pts - 1;
        atomicAdd(&part[batch[pi]], s);          // LDS atomic, 32 bins
    }
    __syncthreads();

    if (t < 64) {
        float v = 0.0f;
        if (t < NB) {
            v = d_out[1 + t] + part[t];          // fold boundary atomics
            d_out[1 + t] = v;
        }
        #pragma unroll
        for (int off = 32; off >= 1; off >>= 1) v += __shfl_xor(v, off, 64);
        if (t == 0) d_out[0] = v * (1.0f / NB);
    }
}

extern "C" void kernel_launch(void* const* d_in, const int* in_sizes, int n_in,
                              void* d_out, int out_size, void* d_ws, size_t ws_size,
                              hipStream_t stream) {
    const float* x        = (const float*)d_in[0];
    const float* vote     = (const float*)d_in[1];
    const float* scales   = (const float*)d_in[2];
    const float* log_pres = (const float*)d_in[3];
    const int*   batch    = (const int*)d_in[4];
    float* out = (float*)d_out;
    float* ws  = (float*)d_ws;

    int n_pts   = in_sizes[0] / 6;
    int n_waves = (n_pts + PPW - 1) / PPW;

    // out re-poisoned to 0xAA before every timed call -> zero it (capture-legal)
    hipMemsetAsync(d_out, 0, (size_t)out_size * sizeof(float), stream);

    int n_blocks = (n_waves + 3) / 4;        // 4 waves (256 threads) per block
    capsule_main<<<n_blocks, 256, 0, stream>>>(x, vote, scales, log_pres, batch,
                                               out + 1, ws, n_pts);

    final_kernel<<<1, 1024, 0, stream>>>(ws, batch, out, n_waves, n_pts);
}